// Round 10
// baseline (163.157 us; speedup 1.0000x reference)
//
#include <hip/hip_runtime.h>
#include <hip/hip_bf16.h>

#define NE 32
#define MM 1024
#define KK 512
#define NN 512
#define BM 256   // rows per tile (vt = ceil(cnt/256) m-tiles per expert)
#define BN 256   // cols per tile -> 2 n-tiles
#define BK 32    // K-step; 16 iterations
#define KKB 2048 // bytes per K-row (KK * 4)

typedef __attribute__((ext_vector_type(8))) short bf16x8;
typedef __attribute__((ext_vector_type(4))) float floatx4;

__device__ __forceinline__ short f2bf(float f) {
  union { __hip_bfloat16 b; short s; } u;
  u.b = __float2bfloat16(f);   // RNE
  return u.s;
}
__device__ __forceinline__ bf16x8 pack8(float4 a, float4 b) {
  return (bf16x8){ f2bf(a.x), f2bf(a.y), f2bf(a.z), f2bf(a.w),
                   f2bf(b.x), f2bf(b.y), f2bf(b.z), f2bf(b.w) };
}

// Fire-and-forget global->LDS DMA (16 B/lane): cannot be sunk by regalloc
// (no register result) -- the ONLY prefetch mechanism that survived compilation
// in 10 rounds (r5/r7 verified; plain-load staging sank in r1/r6/r8/r9).
#define GLDS(g, l) __builtin_amdgcn_global_load_lds(                      \
    (const __attribute__((address_space(1))) void*)(g),                   \
    (__attribute__((address_space(3))) void*)(l), 16, 0, 0)

// FAT TILE (r8's +16us win: 32 MFMA/wave/phase) x DMA+counted-vmcnt (r5's
// verified in-flight mechanism): the untested combination.
// fp32 staging (DMA can't convert); cvt_pk moves to the ds_read path.
// Per expert (XCD-pinned: expert e -> XCD e&7): items = [2*vt GEMM tiles] ++
// [(4-vt) zero 256x512 stripes]; vt+4 <= 8 items -> <=32 slots/XCD, grid 256.
extern "C" __global__ __launch_bounds__(512, 2)
void expert_gemm(const float* __restrict__ A, const float* __restrict__ B,
                 const int* __restrict__ cnts, float* __restrict__ C)
{
  const int b    = blockIdx.x;
  const int tid  = threadIdx.x;
  const int xcd  = b & 7;
  const int slot = b >> 3;

  int e = -1, mt = 0, nt = 0, zfill = 0;
  int base = 0;
#pragma unroll
  for (int i = 0; i < 4; ++i) {
    int ei = xcd + (i << 3);
    int vt = (cnts[ei] + 255) >> 8;    // 256-row tiles with valid rows
    int tot = vt + 4;                  // 2*vt gemm + (4-vt) zero stripes
    if (e < 0 && slot < base + tot) {
      int r = slot - base;
      int g = vt << 1;
      e = ei;
      if (r < g) { mt = r >> 1; nt = r & 1; }
      else       { zfill = 1; mt = vt + (r - g); }
    }
    base += tot;
  }
  if (e < 0) return;   // beyond this XCD's item count (uniform per block)

  if (zfill) {
    // zero-fill a 256x512 stripe (harness poisons d_out each launch)
    float* Ce = C + ((size_t)e * MM + mt * BM) * NN;
    float4 zf = make_float4(0.f, 0.f, 0.f, 0.f);
#pragma unroll
    for (int q = 0; q < 64; ++q) {
      int fidx = q * 512 + tid;
      int r = fidx >> 7, c = (fidx & 127) << 2;
      *(float4*)(Ce + (size_t)r * NN + c) = zf;
    }
    return;
  }

  // ---- GEMM tile: C[e][m0:m0+256][n0:n0+256] = A[e] @ B[e]^T ----
  const int m0 = mt * BM, n0 = nt * BN;
  const int cnt = cnts[e];
  const float* Ae = A + ((size_t)e * MM + m0) * KK;
  const float* Be = B + ((size_t)e * NN + n0) * KK;
  float* Ce = C + ((size_t)e * MM + m0) * NN + n0;

  // fp32 LDS, double-buffered: 2 x (32 KB A + 32 KB B) = 128 KB.
  // Row = 32 floats = 128 B = 8 x 16B units; logical unit u of row r lives at
  // phys unit u ^ (r&7) (source-side swizzle, r4/r5/r7-verified correct).
  __shared__ __align__(16) float sA[2][BM * BK];  // 2 x 32 KB
  __shared__ __align__(16) float sB[2][BN * BK];  // 2 x 32 KB

  const int wave = tid >> 6, lane = tid & 63;
  const int wm = (wave >> 2) * 128, wn = (wave & 3) * 64;  // wave tile: 128x64
  const int fr = lane & 15, kh = lane >> 4;

  // DMA source geometry: one wave-DMA covers 8 rows x 128 B = 1 KB.
  // lane -> row lr in the 8-row group, source unit lu = (lane&7)^lr so that
  // linear LDS phys unit (lane&7) holds logical unit ((lane&7) ^ (row&7)).
  const int lr = lane >> 3;
  const int lu = (lane & 7) ^ lr;
  const size_t rowb = (size_t)lr * KKB + (size_t)lu * 16;  // bytes
  const char* gA = (const char*)Ae;
  const char* gB = (const char*)Be;

  // Per slab: 64 wave-DMAs (A:32 groups, B:32 groups), 8 per wave.
#define STAGE(bufi, KT) do {                                               \
    _Pragma("unroll")                                                      \
    for (int q = 0; q < 4; ++q) {                                          \
      int grp = (wave << 2) + q;                                           \
      GLDS(gA + (size_t)(grp << 3) * KKB + rowb + (size_t)(KT) * 4,        \
           &sA[bufi][grp << 8]);                                           \
      GLDS(gB + (size_t)(grp << 3) * KKB + rowb + (size_t)(KT) * 4,        \
           &sB[bufi][grp << 8]);                                           \
    }                                                                      \
  } while (0)

  floatx4 acc4[8][4] = {};

  STAGE(0, 0);   // slab 0: 8 DMAs/wave in flight

#pragma unroll
  for (int kt = 0; kt < KK; kt += BK) {
    const int cur = (kt >> 5) & 1;

    if (kt + BK < KK) {
      STAGE(cur ^ 1, kt + BK);   // next slab's 8 DMAs join the queue
      // wait ONLY slab k (oldest 8); slab k+1's 8 stay in flight through
      // the entire read/cvt/MFMA phase below
      asm volatile("s_waitcnt vmcnt(8)" ::: "memory");
    } else {
      asm volatile("s_waitcnt vmcnt(0)" ::: "memory");
    }
    __builtin_amdgcn_s_barrier();        // raw: no compiler vmcnt(0) drain
    __builtin_amdgcn_sched_barrier(0);   // no ds_read hoisted above barrier

    const char* bufA = (const char*)sA[cur];
    const char* bufB = (const char*)sB[cur];

    bf16x8 bfv[4];
#pragma unroll
    for (int j = 0; j < 4; ++j) {
      int rB = wn + (j << 4) + fr;
      const char* rb = bufB + rB * 128;
      float4 f0 = *(const float4*)(rb + ((((kh << 1)    ) ^ (rB & 7)) << 4));
      float4 f1 = *(const float4*)(rb + ((((kh << 1) | 1) ^ (rB & 7)) << 4));
      bfv[j] = pack8(f0, f1);
    }
    __builtin_amdgcn_s_setprio(1);
#pragma unroll
    for (int i = 0; i < 8; ++i) {
      int rA = wm + (i << 4) + fr;
      const char* rb = bufA + rA * 128;
      float4 f0 = *(const float4*)(rb + ((((kh << 1)    ) ^ (rA & 7)) << 4));
      float4 f1 = *(const float4*)(rb + ((((kh << 1) | 1) ^ (rA & 7)) << 4));
      bf16x8 af = pack8(f0, f1);
#pragma unroll
      for (int j = 0; j < 4; ++j)
        acc4[i][j] = __builtin_amdgcn_mfma_f32_16x16x32_bf16(af, bfv[j], acc4[i][j], 0, 0, 0);
    }
    __builtin_amdgcn_s_setprio(0);

    if (kt + BK < KK) {
      // next iteration DMAs into buf[cur] (the one just read): all waves must
      // finish reading first (per-wave lgkmcnt already drained before MFMA use)
      __builtin_amdgcn_sched_barrier(0);
      __builtin_amdgcn_s_barrier();
      __builtin_amdgcn_sched_barrier(0);
    }
  }
#undef STAGE

  // epilogue: C/D layout col=lane&15, row=(lane>>4)*4+reg (m89/m91-verified)
  const int rbase = (lane >> 4) << 2;
#pragma unroll
  for (int i = 0; i < 8; ++i) {
#pragma unroll
    for (int r = 0; r < 4; ++r) {
      int row = wm + (i << 4) + rbase + r;
      bool valid = (m0 + row) < cnt;
#pragma unroll
      for (int j = 0; j < 4; ++j) {
        int col = wn + (j << 4) + fr;
        Ce[(size_t)row * NN + col] = valid ? acc4[i][j][r] : 0.0f;
      }
    }
  }
}

extern "C" void kernel_launch(void* const* d_in, const int* in_sizes, int n_in,
                              void* d_out, int out_size, void* d_ws, size_t ws_size,
                              hipStream_t stream) {
  const float* A    = (const float*)d_in[0];
  const float* B    = (const float*)d_in[1];
  const int*   cnts = (const int*)d_in[2];
  float*       C    = (float*)d_out;

  // 8 XCDs x <=32 slots; blockIdx & 7 selects XCD (round-robin dispatch)
  hipLaunchKernelGGL(expert_gemm, dim3(256), dim3(512), 0, stream, A, B, cnts, C);
}